// Round 8
// baseline (195.291 us; speedup 1.0000x reference)
//
#include <hip/hip_runtime.h>
#include <math.h>

// Problem constants (AdaSpatialMLP): B=128, N=196, DIM=384, K=16, H=6, R=4
#define BB  128
#define NN  196
#define CDIM 384
#define KK  16
#define HH  6
#define DR  96    // DIM/R
#define HD  64    // DIM/H
#define MP  208   // padded M (13 x 16) for wbT / A
#define NCHUNK 7  // n chunks of 32 (224 padded n)
#define PLANE 6656  // 32*MP elems: h-plane stride within one (b,nc) slab of A

typedef __attribute__((ext_vector_type(8))) short bf16x8;
typedef __attribute__((ext_vector_type(4))) float f32x4;

__device__ __forceinline__ unsigned short f2bf(float f) {
    unsigned u = __float_as_uint(f);
    u += 0x7FFFu + ((u >> 16) & 1u);   // RNE
    return (unsigned short)(u >> 16);
}
__device__ __forceinline__ unsigned pk2bf(float lo, float hi) {
    return (unsigned)f2bf(lo) | ((unsigned)f2bf(hi) << 16);
}

union AFrag { unsigned u[4]; bf16x8 f; };

// ---------------------------------------------------------------------------
// Prep: W1T[c][k] bf16 (96x384), W2T[c][k] bf16 (96x96), and padded
// wbT[n(224)][m(208)][k16] bf16 so producer loads are unconditional 16B frags.
// Pad region is zero-filled (-> A=0 there, harmless).
// ---------------------------------------------------------------------------
__global__ __launch_bounds__(256) void prep_kernel(
    const float* __restrict__ W1, const float* __restrict__ W2,
    const float* __restrict__ wb,
    unsigned short* __restrict__ W1T, unsigned short* __restrict__ W2T,
    unsigned short* __restrict__ wbT)
{
    const int bid = blockIdx.x;
    const int t   = threadIdx.x;
    if (bid < DR) {
        const int c = bid;     // 0..95
        for (int k = t; k < CDIM; k += 256)
            W1T[(size_t)c * CDIM + k] = f2bf(W1[(size_t)k * DR + c]);
        if (t < DR)
            W2T[(size_t)c * DR + t] = f2bf(W2[(size_t)t * DR + c]);
    } else {
        const int n = bid - DR;  // 0..223
        const int m = t;
        if (m < MP) {
            unsigned o[8] = {0u, 0u, 0u, 0u, 0u, 0u, 0u, 0u};
            if (n < NN && m < NN) {
                #pragma unroll
                for (int j = 0; j < 8; ++j) {
                    const float a = wb[((size_t)(2 * j)     * NN + n) * NN + m];
                    const float c = wb[((size_t)(2 * j + 1) * NN + n) * NN + m];
                    o[j] = pk2bf(a, c);
                }
            }
            unsigned* dst = (unsigned*)(wbT + ((size_t)n * MP + m) * KK);
            *(uint4*)dst       = make_uint4(o[0], o[1], o[2], o[3]);
            *(uint4*)(dst + 4) = make_uint4(o[4], o[5], o[6], o[7]);
        }
    }
}

// ---------------------------------------------------------------------------
// Fused adapter + A-form: one block per (b, nc), 256 thr (4 waves).
// Phase 1: mix[n0..n0+31][h][k] (GEMM1 -> GELU -> GEMM2 -> softmax) in LDS.
// Phase 2: barriered LDS pipeline for wbT (round 7; measured equal-best
//   ~71 us). wbT staged in wbuf[2][2][208][16] double buffer via
//   global->reg(uint4 x4)->LDS; next round's loads issued before compute;
//   A-frags from ds_read_b128. Round-0 loads issued BEFORE phase 1.
//   MFMA: swapped operands, C rows = m -> 8-B packed stores.
// ---------------------------------------------------------------------------
__global__ __launch_bounds__(256, 4) void mixa_kernel(
    const float* __restrict__ x,  const unsigned short* __restrict__ W1T,
    const float* __restrict__ b1, const unsigned short* __restrict__ W2T,
    const float* __restrict__ b2, const unsigned short* __restrict__ wbT,
    unsigned short* __restrict__ A)
{
    __shared__ unsigned short hidb[32][104];       // 6656 B
    __shared__ unsigned short msc[32][96];         // 6144 B
    __shared__ unsigned short wbuf[2][2][208][16]; // 26624 B (2 bufs x 2 n-rows)

    const int t    = threadIdx.x;
    const int w    = t >> 6;        // wave 0..3
    const int wm   = w & 1;         // row half (phase 1)
    const int wc   = w >> 1;        // col half (phase 1)
    const int lane = t & 63;
    const int l15  = lane & 15;
    const int lq   = lane >> 4;
    const int b    = blockIdx.x & 127;   // bid%8 == b%8 -> per-b XCD locality
    const int nc   = blockIdx.x >> 7;
    const int n0   = nc * 32;

    // ---- prestage round-0 wbT chunk (2 n-rows = 13312 B) into regs ----
    const unsigned short* slab = wbT + (size_t)n0 * (MP * KK);  // 32 rows, contiguous
    uint4 av0, av1, av2, av3;
    {
        const uint4* sp = (const uint4*)slab;
        av0 = sp[t];
        av1 = sp[t + 256];
        av2 = sp[t + 512];
        av3 = (t < 64) ? sp[t + 768] : make_uint4(0u, 0u, 0u, 0u);
    }

    // ---- GEMM1: hid = gelu(x @ W1 + b1); rows wm*16+l15 (n-local), 96 cols
    f32x4 acc[3];
    #pragma unroll
    for (int ct = 0; ct < 3; ++ct) {
        const float bj = b1[wc * 48 + ct * 16 + l15];
        acc[ct] = (f32x4){bj, bj, bj, bj};
    }
    const int nrow = n0 + wm * 16 + l15;
    const bool rv  = (nrow < NN);
    const float* xrow = x + ((size_t)b * NN + nrow) * CDIM;
    float4 u = make_float4(0.f, 0.f, 0.f, 0.f);
    float4 v = make_float4(0.f, 0.f, 0.f, 0.f);
    if (rv) {
        u = *(const float4*)(xrow + 8 * lq);
        v = *(const float4*)(xrow + 8 * lq + 4);
    }
    for (int kc = 0; kc < CDIM; kc += 32) {
        // prefetch next iteration's x before consuming current
        float4 un = make_float4(0.f, 0.f, 0.f, 0.f);
        float4 vn = make_float4(0.f, 0.f, 0.f, 0.f);
        if (rv && kc + 32 < CDIM) {
            un = *(const float4*)(xrow + kc + 32 + 8 * lq);
            vn = *(const float4*)(xrow + kc + 32 + 8 * lq + 4);
        }
        AFrag af;
        af.u[0] = pk2bf(u.x, u.y); af.u[1] = pk2bf(u.z, u.w);
        af.u[2] = pk2bf(v.x, v.y); af.u[3] = pk2bf(v.z, v.w);
        #pragma unroll
        for (int ct = 0; ct < 3; ++ct) {
            const bf16x8 bf = *(const bf16x8*)(W1T + (size_t)(wc * 48 + ct * 16 + l15) * CDIM + kc + 8 * lq);
            acc[ct] = __builtin_amdgcn_mfma_f32_16x16x32_bf16(af.f, bf, acc[ct], 0, 0, 0);
        }
        u = un; v = vn;
    }
    #pragma unroll
    for (int ct = 0; ct < 3; ++ct)
        #pragma unroll
        for (int r = 0; r < 4; ++r) {
            const float vv = acc[ct][r];
            hidb[wm * 16 + lq * 4 + r][wc * 48 + ct * 16 + l15] =
                f2bf(0.5f * vv * (1.0f + erff(vv * 0.70710678118654752f)));
        }
    __syncthreads();

    // ---- GEMM2: logits = hid @ W2 + b2 ----
    f32x4 acc2[3];
    #pragma unroll
    for (int ct = 0; ct < 3; ++ct) {
        const float bj = b2[wc * 48 + ct * 16 + l15];
        acc2[ct] = (f32x4){bj, bj, bj, bj};
    }
    #pragma unroll
    for (int kc = 0; kc < DR; kc += 32) {
        const bf16x8 af = *(const bf16x8*)&hidb[wm * 16 + l15][kc + 8 * lq];
        #pragma unroll
        for (int ct = 0; ct < 3; ++ct) {
            const bf16x8 bf = *(const bf16x8*)(W2T + (size_t)(wc * 48 + ct * 16 + l15) * DR + kc + 8 * lq);
            acc2[ct] = __builtin_amdgcn_mfma_f32_16x16x32_bf16(af, bf, acc2[ct], 0, 0, 0);
        }
    }
    __syncthreads();   // all hidb reads done; reuse as logits buffer

    #pragma unroll
    for (int ct = 0; ct < 3; ++ct)
        #pragma unroll
        for (int r = 0; r < 4; ++r)
            hidb[wm * 16 + lq * 4 + r][wc * 48 + ct * 16 + l15] = f2bf(acc2[ct][r]);
    __syncthreads();

    // ---- softmax over k (logit col = k*6+h) -> msc[n][h*16+k] bf16 ----
    if (t < 192) {
        const int r = t / 6, h = t - r * 6;
        float lg[KK];
        float mx = -1e30f;
        #pragma unroll
        for (int k = 0; k < KK; ++k) {
            lg[k] = __uint_as_float((unsigned)hidb[r][6 * k + h] << 16);
            mx = fmaxf(mx, lg[k]);
        }
        float s = 0.f;
        #pragma unroll
        for (int k = 0; k < KK; ++k) { lg[k] = __expf(lg[k] - mx); s += lg[k]; }
        const float inv = 1.0f / s;
        unsigned o[8];
        #pragma unroll
        for (int jj = 0; jj < 8; ++jj)
            o[jj] = pk2bf(lg[2 * jj] * inv, lg[2 * jj + 1] * inv);
        unsigned* op = (unsigned*)&msc[r][16 * h];
        *(uint4*)op       = make_uint4(o[0], o[1], o[2], o[3]);
        *(uint4*)(op + 4) = make_uint4(o[4], o[5], o[6], o[7]);
    }
    __syncthreads();

    // ---- Phase 2: LDS-pipelined A-form producer ----
    const bf16x8 z8 = {0, 0, 0, 0, 0, 0, 0, 0};
    const f32x4  cz = {0.f, 0.f, 0.f, 0.f};
    const size_t bc6 = ((size_t)b * NCHUNK + nc) * HH;
    const int  rw  = w >> 1;              // n-row within pair (0/1)
    const int  mh  = w & 1;               // m-half: 0 -> tiles 0..6, 1 -> 7..12
    const bool hv  = (l15 < HH);          // valid h column
    const bool kv  = (lq < 2);            // lanes holding k<16 (others annihilated)

    for (int r = 0; r < 16; ++r) {
        if (r) __syncthreads();           // round r-1 compute done

        // ---- write staged regs -> wbuf[r&1] (linear copy) ----
        {
            uint4* dp = (uint4*)&wbuf[r & 1][0][0][0];
            dp[t]       = av0;
            dp[t + 256] = av1;
            dp[t + 512] = av2;
            if (t < 64) dp[t + 768] = av3;
        }
        // ---- issue next round's global loads BEFORE compute ----
        if (r + 1 < 16) {
            const uint4* sp = (const uint4*)slab + (size_t)(r + 1) * 832;
            av0 = sp[t];
            av1 = sp[t + 256];
            av2 = sp[t + 512];
            if (t < 64) av3 = sp[t + 768];
        }
        __syncthreads();                  // wbuf[r&1] ready

        // ---- compute: n-row nl = 2r + rw; 7 (mh=0) / 6 (mh=1) m-tiles ----
        const int nl = 2 * r + rw;
        const bf16x8 bmix = (hv && kv)
            ? *(const bf16x8*)&msc[nl][l15 * 16 + 8 * lq] : z8;
        const unsigned short* wrow = &wbuf[r & 1][rw][0][0];   // 208 x 16
        unsigned short* p0 = A + (bc6 + l15) * PLANE + (size_t)nl * MP + lq * 4;
        if (mh == 0) {
            #pragma unroll
            for (int mt = 0; mt < 7; ++mt) {
                const bf16x8 afr = *(const bf16x8*)(wrow + (mt * 16 + l15) * 16 + 8 * lq);
                const f32x4 c = __builtin_amdgcn_mfma_f32_16x16x32_bf16(afr, bmix, cz, 0, 0, 0);
                if (hv)   // 4 consecutive m -> one 8B store
                    *(uint2*)(p0 + mt * 16) =
                        make_uint2(pk2bf(c[0], c[1]), pk2bf(c[2], c[3]));
            }
        } else {
            #pragma unroll
            for (int mt = 7; mt < 13; ++mt) {
                const bf16x8 afr = *(const bf16x8*)(wrow + (mt * 16 + l15) * 16 + 8 * lq);
                const f32x4 c = __builtin_amdgcn_mfma_f32_16x16x32_bf16(afr, bmix, cz, 0, 0, 0);
                if (hv)
                    *(uint2*)(p0 + mt * 16) =
                        make_uint2(pk2bf(c[0], c[1]), pk2bf(c[2], c[3]));
            }
        }
    }
}

// ---------------------------------------------------------------------------
// Consumer GEMM — EXACT round-2 form (measured 46.6-47.8 us, 2.08 TB/s).
// Round-3/4 added an A-prefetch prologue + sched_barrier(0) that was never
// re-measured (fell below top-5 cutoff) and likely regressed it ~23 us
// (order-pinning defeats the compiler's ds_read/MFMA scheduling). Reverted.
// ---------------------------------------------------------------------------
__global__ __launch_bounds__(192, 3) void mix_gemm_kernel(
    const float* __restrict__ x, const unsigned short* __restrict__ Ab,
    float* __restrict__ out)
{
    __shared__ unsigned short xT[192][40];   // [c_local][n] bf16, 15360 B
    __shared__ unsigned short As[3][32][68]; // [h_local][n][m_local] bf16, 13056 B

    const int t    = threadIdx.x;
    const int bid  = blockIdx.x;
    const int b    = bid & 127;       // bid%8 == b%8 -> same-b blocks share an XCD
    const int sub  = bid >> 7;        // 0..7
    const int q    = sub >> 1;        // m-quarter
    const int hp   = sub & 1;         // head triple
    const int m0   = q * 52;
    const int qvalid = (q == 3) ? 40 : 52;
    const int lw   = t >> 6;          // local head 0..2
    const int hbase = hp * 3;
    const int lane = t & 63;
    const int l15  = lane & 15;
    const int lq   = lane >> 4;
    const int c0   = hp * 192;        // channel slice of this head triple

    const f32x4 cz = {0.f, 0.f, 0.f, 0.f};
    f32x4 acc[4][4];
    #pragma unroll
    for (int mt = 0; mt < 4; ++mt)
        #pragma unroll
        for (int ct = 0; ct < 4; ++ct) acc[mt][ct] = cz;

    for (int nc = 0; nc < NCHUNK; ++nc) {
        const int n0 = nc * 32;
        __syncthreads();   // previous chunk's MFMA reads done

        // ---- A-slab loads: 96 rows (3h x 32n) x 128B, coalesced u64 ----
        unsigned long long av[8];
        const size_t bc6 = ((size_t)b * NCHUNK + nc) * HH + hbase;
        #pragma unroll
        for (int i = 0; i < 8; ++i) {
            const int P = t + 192 * i;        // 0..1535
            const int row = P >> 4, p = P & 15;
            const int hl = row >> 5, n = row & 31;
            av[i] = *(const unsigned long long*)(
                Ab + (bc6 + hl) * PLANE + (size_t)n * MP + m0 + 4 * p);
        }

        // ---- stage x -> xT bf16 transposed (this triple's 192 channels) ----
        #pragma unroll
        for (int it = 0; it < 4; ++it) {
            const int task = t + 192 * it;      // 0..767
            const int p  = task & 15;           // n-pair 0..15
            const int cq = task >> 4;           // c-quad 0..47
            const int n  = n0 + 2 * p;
            float4 va = make_float4(0.f, 0.f, 0.f, 0.f);
            float4 vb = make_float4(0.f, 0.f, 0.f, 0.f);
            if (n < NN)     va = *(const float4*)(x + ((size_t)b * NN + n) * CDIM + c0 + 4 * cq);
            if (n + 1 < NN) vb = *(const float4*)(x + ((size_t)b * NN + n + 1) * CDIM + c0 + 4 * cq);
            *(unsigned*)&xT[4 * cq + 0][2 * p] = pk2bf(va.x, vb.x);
            *(unsigned*)&xT[4 * cq + 1][2 * p] = pk2bf(va.y, vb.y);
            *(unsigned*)&xT[4 * cq + 2][2 * p] = pk2bf(va.z, vb.z);
            *(unsigned*)&xT[4 * cq + 3][2 * p] = pk2bf(va.w, vb.w);
        }

        // ---- write A-slab to LDS (8B stores, conflict-free) ----
        #pragma unroll
        for (int i = 0; i < 8; ++i) {
            const int P = t + 192 * i;
            const int row = P >> 4, p = P & 15;
            *(unsigned long long*)&As[row >> 5][row & 31][4 * p] = av[i];
        }
        __syncthreads();

        // ---- A-frags via u16 gathers (transpose-on-read), then 16 MFMA ----
        bf16x8 afr[4], bfr[4];
        #pragma unroll
        for (int mt = 0; mt < 4; ++mt) {
            union { unsigned short s[8]; bf16x8 v; } u;
            #pragma unroll
            for (int j = 0; j < 8; ++j)
                u.s[j] = As[lw][8 * lq + j][mt * 16 + l15];
            afr[mt] = u.v;
        }
        #pragma unroll
        for (int ct = 0; ct < 4; ++ct)
            bfr[ct] = *(const bf16x8*)&xT[lw * 64 + ct * 16 + l15][8 * lq];
        #pragma unroll
        for (int mt = 0; mt < 4; ++mt)
            #pragma unroll
            for (int ct = 0; ct < 4; ++ct)
                acc[mt][ct] = __builtin_amdgcn_mfma_f32_16x16x32_bf16(
                    afr[mt], bfr[ct], acc[mt][ct], 0, 0, 0);
    }

    // ---- epilogue: C/D layout col=l15 (c), row=lq*4+r (m) ----
    const int h = hbase + lw;
    #pragma unroll
    for (int mt = 0; mt < 4; ++mt) {
        #pragma unroll
        for (int r = 0; r < 4; ++r) {
            const int ms = mt * 16 + lq * 4 + r;
            if (ms < qvalid) {
                float* op = out + ((size_t)b * NN + m0 + ms) * CDIM + h * HD + l15;
                #pragma unroll
                for (int ct = 0; ct < 4; ++ct)
                    op[ct * 16] = acc[mt][ct][r];
            }
        }
    }
}

// ---------------------------------------------------------------------------
// Fallback path (small workspace): standalone adapter + fused mix kernel.
// ---------------------------------------------------------------------------
__global__ __launch_bounds__(128, 3) void adapter_kernel(
    const float* __restrict__ x,   const unsigned short* __restrict__ W1T,
    const float* __restrict__ b1,  const unsigned short* __restrict__ W2T,
    const float* __restrict__ b2,  unsigned short* __restrict__ mix_out)
{
    __shared__ unsigned short hidb[16][104];

    const int t    = threadIdx.x;
    const int wc   = t >> 6;
    const int lane = t & 63;
    const int l15  = lane & 15;
    const int lq   = lane >> 4;
    const int row0 = blockIdx.x * 16;

    f32x4 acc[3];
    #pragma unroll
    for (int ct = 0; ct < 3; ++ct) {
        const float bj = b1[wc * 48 + ct * 16 + l15];
        acc[ct] = (f32x4){bj, bj, bj, bj};
    }
    const float* xrow = x + (size_t)(row0 + l15) * CDIM;
    for (int kc = 0; kc < CDIM; kc += 32) {
        const float4 u = *(const float4*)(xrow + kc + 8 * lq);
        const float4 v = *(const float4*)(xrow + kc + 8 * lq + 4);
        AFrag af;
        af.u[0] = pk2bf(u.x, u.y); af.u[1] = pk2bf(u.z, u.w);
        af.u[2] = pk2bf(v.x, v.y); af.u[3] = pk2bf(v.z, v.w);
        #pragma unroll
        for (int ct = 0; ct < 3; ++ct) {
            const bf16x8 bf = *(const bf16x8*)(W1T + (size_t)(wc * 48 + ct * 16 + l15) * CDIM + kc + 8 * lq);
            acc[ct] = __builtin_amdgcn_mfma_f32_16x16x32_bf16(af.f, bf, acc[ct], 0, 0, 0);
        }
    }
    #pragma unroll
    for (int ct = 0; ct < 3; ++ct)
        #pragma unroll
        for (int r = 0; r < 4; ++r) {
            const float vv = acc[ct][r];
            hidb[lq * 4 + r][wc * 48 + ct * 16 + l15] =
                f2bf(0.5f * vv * (1.0f + erff(vv * 0.70710678118654752f)));
        }
    __syncthreads();

    f32x4 acc2[3];
    #pragma unroll
    for (int ct = 0; ct < 3; ++ct) {
        const float bj = b2[wc * 48 + ct * 16 + l15];
        acc2[ct] = (f32x4){bj, bj, bj, bj};
    }
    #pragma unroll
    for (int kc = 0; kc < DR; kc += 32) {
        const bf16x8 af = *(const bf16x8*)&hidb[l15][kc + 8 * lq];
        #pragma unroll
        for (int ct = 0; ct < 3; ++ct) {
            const bf16x8 bf = *(const bf16x8*)(W2T + (size_t)(wc * 48 + ct * 16 + l15) * DR + kc + 8 * lq);
            acc2[ct] = __builtin_amdgcn_mfma_f32_16x16x32_bf16(af, bf, acc2[ct], 0, 0, 0);
        }
    }
    __syncthreads();

    #pragma unroll
    for (int ct = 0; ct < 3; ++ct)
        #pragma unroll
        for (int r = 0; r < 4; ++r)
            hidb[lq * 4 + r][wc * 48 + ct * 16 + l15] = f2bf(acc2[ct][r]);
    __syncthreads();

    if (t < 96) {
        const int r = t / 6, h = t % 6;
        float lg[KK];
        float mx = -1e30f;
        #pragma unroll
        for (int k = 0; k < KK; ++k) {
            lg[k] = __uint_as_float((unsigned)hidb[r][6 * k + h] << 16);
            mx = fmaxf(mx, lg[k]);
        }
        float s = 0.f;
        #pragma unroll
        for (int k = 0; k < KK; ++k) { lg[k] = __expf(lg[k] - mx); s += lg[k]; }
        const float inv = 1.0f / s;
        unsigned o[8];
        #pragma unroll
        for (int jj = 0; jj < 8; ++jj)
            o[jj] = pk2bf(lg[2 * jj] * inv, lg[2 * jj + 1] * inv);
        unsigned* op = (unsigned*)(mix_out + ((size_t)(row0 + r) * HH + h) * KK);
        *(uint4*)op       = make_uint4(o[0], o[1], o[2], o[3]);
        *(uint4*)(op + 4) = make_uint4(o[4], o[5], o[6], o[7]);
    }
}

__global__ __launch_bounds__(192, 3) void mix_mfma_fb_kernel(
    const float* __restrict__ x,  const unsigned short* __restrict__ mixb,
    const unsigned short* __restrict__ wbT, float* __restrict__ out)
{
    __shared__ unsigned short xT[192][40];
    __shared__ unsigned short Asb[3][64][40];

    const int t    = threadIdx.x;
    const int bid  = blockIdx.x;
    const int b    = bid & 127;
    const int sub  = bid >> 7;
    const int q    = sub >> 1;
    const int hp   = sub & 1;
    const int m0   = q * 52;
    const int qvalid = (q == 3) ? 40 : 52;
    const int lw   = t >> 6;
    const int hbase = hp * 3;
    const int lane = t & 63;
    const int l15  = lane & 15;
    const int lq   = lane >> 4;
    const int c0   = hp * 192;

    const bf16x8 z8 = {0, 0, 0, 0, 0, 0, 0, 0};
    const f32x4  cz = {0.f, 0.f, 0.f, 0.f};

    f32x4 acc[4][4];
    #pragma unroll
    for (int mt = 0; mt < 4; ++mt)
        #pragma unroll
        for (int ct = 0; ct < 4; ++ct) acc[mt][ct] = cz;

    for (int nc = 0; nc < 7; ++nc) {
        const int n0 = nc * 32;
        __syncthreads();

        #pragma unroll
        for (int it = 0; it < 4; ++it) {
            const int task = t + 192 * it;
            const int p  = task & 15;
            const int cq = task >> 4;
            const int n  = n0 + 2 * p;
            float4 va = make_float4(0.f, 0.f, 0.f, 0.f);
            float4 vb = make_float4(0.f, 0.f, 0.f, 0.f);
            if (n < NN)     va = *(const float4*)(x + ((size_t)b * NN + n) * CDIM + c0 + 4 * cq);
            if (n + 1 < NN) vb = *(const float4*)(x + ((size_t)b * NN + n + 1) * CDIM + c0 + 4 * cq);
            *(unsigned*)&xT[4 * cq + 0][2 * p] = pk2bf(va.x, vb.x);
            *(unsigned*)&xT[4 * cq + 1][2 * p] = pk2bf(va.y, vb.y);
            *(unsigned*)&xT[4 * cq + 2][2 * p] = pk2bf(va.z, vb.z);
            *(unsigned*)&xT[4 * cq + 3][2 * p] = pk2bf(va.w, vb.w);
        }

        for (int nl = lw; nl < 32; nl += 3) {
            const int n = n0 + nl;
            if (n < NN) {
                bf16x8 af = z8;
                if (l15 < HH && lq < 2)
                    af = *(const bf16x8*)(mixb + (((size_t)b * NN + n) * HH + l15) * KK + 8 * lq);
                #pragma unroll
                for (int mt = 0; mt < 4; ++mt) {
                    const int m = m0 + mt * 16 + l15;
                    bf16x8 bf = z8;
                    if (lq < 2 && m < NN)
                        bf = *(const bf16x8*)(wbT + ((size_t)n * MP + m) * KK + 8 * lq);
                    const f32x4 c = __builtin_amdgcn_mfma_f32_16x16x32_bf16(af, bf, cz, 0, 0, 0);
                    #pragma unroll
                    for (int r = 0; r < 4; ++r) {
                        const int hh = lq * 4 + r;
                        if (hh >= hbase && hh < hbase + 3)
                            Asb[hh - hbase][mt * 16 + l15][nl] = f2bf(c[r]);
                    }
                }
            } else {
                #pragma unroll
                for (int mt = 0; mt < 4; ++mt)
                    #pragma unroll
                    for (int r = 0; r < 4; ++r) {
                        const int hh = lq * 4 + r;
                        if (hh >= hbase && hh < hbase + 3)
                            Asb[hh - hbase][mt * 16 + l15][nl] = 0;
                    }
            }
        }
        __syncthreads();

        bf16x8 afr[4], bfr[4];
        #pragma unroll
        for (int mt = 0; mt < 4; ++mt)
            afr[mt] = *(const bf16x8*)&Asb[lw][mt * 16 + l15][8 * lq];
        #pragma unroll
        for (int ct = 0; ct < 4; ++ct)
            bfr[ct] = *(const bf16x8*)&xT[lw * 64 + ct * 16 + l15][8 * lq];
        #pragma unroll
        for (int mt = 0; mt < 4; ++mt)
            #pragma unroll
            for (int ct = 0; ct < 4; ++ct)
                acc[mt][ct] = __builtin_amdgcn_mfma_f32_16x16x32_bf16(
                    afr[mt], bfr[ct], acc[mt][ct], 0, 0, 0);
    }

    const int h = hbase + lw;
    #pragma unroll
    for (int mt = 0; mt < 4; ++mt) {
        #pragma unroll
        for (int r = 0; r < 4; ++r) {
            const int ms = mt * 16 + lq * 4 + r;
            if (ms < qvalid) {
                float* op = out + ((size_t)b * NN + m0 + ms) * CDIM + h * HD + l15;
                #pragma unroll
                for (int ct = 0; ct < 4; ++ct)
                    op[ct * 16] = acc[mt][ct][r];
            }
        }
    }
}

extern "C" void kernel_launch(void* const* d_in, const int* in_sizes, int n_in,
                              void* d_out, int out_size, void* d_ws, size_t ws_size,
                              hipStream_t stream) {
    (void)in_sizes; (void)n_in; (void)out_size;
    const float* x  = (const float*)d_in[0];
    const float* W1 = (const float*)d_in[1];
    const float* b1 = (const float*)d_in[2];
    const float* W2 = (const float*)d_in[3];
    const float* b2 = (const float*)d_in[4];
    const float* wb = (const float*)d_in[5];
    float* out = (float*)d_out;

    // workspace layout (1KB slack after wbT for unconditional tail overread)
    const size_t W1T_OFF  = 0;                 //    73,728 B
    const size_t W2T_OFF  = 73728;             //    18,432 B
    const size_t WBT_OFF  = 92160;             // 1,490,944 B (224*208*16*2)
    const size_t A_OFF    = 1584128;           // 71,565,312 B
    const size_t NEED     = A_OFF + 71565312ull + 1024ull;

    unsigned short* w1t = (unsigned short*)((char*)d_ws + W1T_OFF);
    unsigned short* w2t = (unsigned short*)((char*)d_ws + W2T_OFF);
    unsigned short* wbt = (unsigned short*)((char*)d_ws + WBT_OFF);

    prep_kernel<<<DR + 224, 256, 0, stream>>>(W1, W2, wb, w1t, w2t, wbt);

    if (ws_size >= NEED) {
        unsigned short* Ab = (unsigned short*)((char*)d_ws + A_OFF);
        mixa_kernel<<<BB * NCHUNK, 256, 0, stream>>>(x, w1t, b1, w2t, b2, wbt, Ab);
        mix_gemm_kernel<<<8 * BB, 192, 0, stream>>>(x, Ab, out);
    } else {
        unsigned short* mixbuf = (unsigned short*)((char*)d_ws + A_OFF);  // reuse
        adapter_kernel<<<(BB * NN) / 16, 128, 0, stream>>>(x, w1t, b1, w2t, b2, mixbuf);
        mix_mfma_fb_kernel<<<8 * BB, 192, 0, stream>>>(x, mixbuf, wbt, out);
    }
}

// Round 9
// 188.093 us; speedup vs baseline: 1.0383x; 1.0383x over previous
//
#include <hip/hip_runtime.h>
#include <math.h>

// Problem constants (AdaSpatialMLP): B=128, N=196, DIM=384, K=16, H=6, R=4
#define BB  128
#define NN  196
#define CDIM 384
#define KK  16
#define HH  6
#define DR  96    // DIM/R
#define HD  64    // DIM/H
#define MP  208   // padded M (13 x 16) for wbT / A
#define NCHUNK 7  // n chunks of 32 (224 padded n)
#define PLANE 6656  // 32*MP elems: h-plane stride within one (b,nc) slab of A

typedef __attribute__((ext_vector_type(8))) short bf16x8;
typedef __attribute__((ext_vector_type(4))) float f32x4;

__device__ __forceinline__ unsigned short f2bf(float f) {
    unsigned u = __float_as_uint(f);
    u += 0x7FFFu + ((u >> 16) & 1u);   // RNE
    return (unsigned short)(u >> 16);
}
__device__ __forceinline__ unsigned pk2bf(float lo, float hi) {
    return (unsigned)f2bf(lo) | ((unsigned)f2bf(hi) << 16);
}

union AFrag { unsigned u[4]; bf16x8 f; };

// ---------------------------------------------------------------------------
// Prep: W1T[c][k] bf16 (96x384), W2T[c][k] bf16 (96x96), and padded
// wbT[n(224)][m(208)][k16] bf16 so producer loads are unconditional 16B frags.
// Pad region is zero-filled (-> A=0 there, harmless).
// ---------------------------------------------------------------------------
__global__ __launch_bounds__(256) void prep_kernel(
    const float* __restrict__ W1, const float* __restrict__ W2,
    const float* __restrict__ wb,
    unsigned short* __restrict__ W1T, unsigned short* __restrict__ W2T,
    unsigned short* __restrict__ wbT)
{
    const int bid = blockIdx.x;
    const int t   = threadIdx.x;
    if (bid < DR) {
        const int c = bid;     // 0..95
        for (int k = t; k < CDIM; k += 256)
            W1T[(size_t)c * CDIM + k] = f2bf(W1[(size_t)k * DR + c]);
        if (t < DR)
            W2T[(size_t)c * DR + t] = f2bf(W2[(size_t)t * DR + c]);
    } else {
        const int n = bid - DR;  // 0..223
        const int m = t;
        if (m < MP) {
            unsigned o[8] = {0u, 0u, 0u, 0u, 0u, 0u, 0u, 0u};
            if (n < NN && m < NN) {
                #pragma unroll
                for (int j = 0; j < 8; ++j) {
                    const float a = wb[((size_t)(2 * j)     * NN + n) * NN + m];
                    const float c = wb[((size_t)(2 * j + 1) * NN + n) * NN + m];
                    o[j] = pk2bf(a, c);
                }
            }
            unsigned* dst = (unsigned*)(wbT + ((size_t)n * MP + m) * KK);
            *(uint4*)dst       = make_uint4(o[0], o[1], o[2], o[3]);
            *(uint4*)(dst + 4) = make_uint4(o[4], o[5], o[6], o[7]);
        }
    }
}

// ---------------------------------------------------------------------------
// Fused adapter + A-form: one block per (b, nc), 256 thr (4 waves).
// Phase 1: mix[n0..n0+31][h][k] (GEMM1 -> GELU -> GEMM2 -> softmax) in LDS.
// Phase 2: barriered LDS pipeline for wbT (round 7) + ROUND-9 CHANGE:
//   MFMA results land in abuf (5KB LDS, overlaid on dead hidb) instead of
//   scattered 32B global segments; a cooperative copy-out streams abuf to
//   global as 12 x 416B fully-contiguous runs per round, overlapped with
//   the load-issue slot. Decisive test of the "scattered A-writes clamp
//   phase 2 at ~50us" theory (4 structures all landed at ~71us total).
// ---------------------------------------------------------------------------
__global__ __launch_bounds__(256, 4) void mixa_kernel(
    const float* __restrict__ x,  const unsigned short* __restrict__ W1T,
    const float* __restrict__ b1, const unsigned short* __restrict__ W2T,
    const float* __restrict__ b2, const unsigned short* __restrict__ wbT,
    unsigned short* __restrict__ A)
{
    __shared__ unsigned short hidb[32][104];       // 6656 B (abuf overlay in ph2)
    __shared__ unsigned short msc[32][96];         // 6144 B
    __shared__ unsigned short wbuf[2][2][208][16]; // 26624 B (2 bufs x 2 n-rows)

    const int t    = threadIdx.x;
    const int w    = t >> 6;        // wave 0..3
    const int wm   = w & 1;         // row half (phase 1)
    const int wc   = w >> 1;        // col half (phase 1)
    const int lane = t & 63;
    const int l15  = lane & 15;
    const int lq   = lane >> 4;
    const int b    = blockIdx.x & 127;   // bid%8 == b%8 -> per-b XCD locality
    const int nc   = blockIdx.x >> 7;
    const int n0   = nc * 32;

    // ---- prestage round-0 wbT chunk (2 n-rows = 13312 B) into regs ----
    const unsigned short* slab = wbT + (size_t)n0 * (MP * KK);  // 32 rows, contiguous
    uint4 av0, av1, av2, av3;
    {
        const uint4* sp = (const uint4*)slab;
        av0 = sp[t];
        av1 = sp[t + 256];
        av2 = sp[t + 512];
        av3 = (t < 64) ? sp[t + 768] : make_uint4(0u, 0u, 0u, 0u);
    }

    // ---- GEMM1: hid = gelu(x @ W1 + b1); rows wm*16+l15 (n-local), 96 cols
    f32x4 acc[3];
    #pragma unroll
    for (int ct = 0; ct < 3; ++ct) {
        const float bj = b1[wc * 48 + ct * 16 + l15];
        acc[ct] = (f32x4){bj, bj, bj, bj};
    }
    const int nrow = n0 + wm * 16 + l15;
    const bool rv  = (nrow < NN);
    const float* xrow = x + ((size_t)b * NN + nrow) * CDIM;
    float4 u = make_float4(0.f, 0.f, 0.f, 0.f);
    float4 v = make_float4(0.f, 0.f, 0.f, 0.f);
    if (rv) {
        u = *(const float4*)(xrow + 8 * lq);
        v = *(const float4*)(xrow + 8 * lq + 4);
    }
    for (int kc = 0; kc < CDIM; kc += 32) {
        // prefetch next iteration's x before consuming current
        float4 un = make_float4(0.f, 0.f, 0.f, 0.f);
        float4 vn = make_float4(0.f, 0.f, 0.f, 0.f);
        if (rv && kc + 32 < CDIM) {
            un = *(const float4*)(xrow + kc + 32 + 8 * lq);
            vn = *(const float4*)(xrow + kc + 32 + 8 * lq + 4);
        }
        AFrag af;
        af.u[0] = pk2bf(u.x, u.y); af.u[1] = pk2bf(u.z, u.w);
        af.u[2] = pk2bf(v.x, v.y); af.u[3] = pk2bf(v.z, v.w);
        #pragma unroll
        for (int ct = 0; ct < 3; ++ct) {
            const bf16x8 bf = *(const bf16x8*)(W1T + (size_t)(wc * 48 + ct * 16 + l15) * CDIM + kc + 8 * lq);
            acc[ct] = __builtin_amdgcn_mfma_f32_16x16x32_bf16(af.f, bf, acc[ct], 0, 0, 0);
        }
        u = un; v = vn;
    }
    #pragma unroll
    for (int ct = 0; ct < 3; ++ct)
        #pragma unroll
        for (int r = 0; r < 4; ++r) {
            const float vv = acc[ct][r];
            hidb[wm * 16 + lq * 4 + r][wc * 48 + ct * 16 + l15] =
                f2bf(0.5f * vv * (1.0f + erff(vv * 0.70710678118654752f)));
        }
    __syncthreads();

    // ---- GEMM2: logits = hid @ W2 + b2 ----
    f32x4 acc2[3];
    #pragma unroll
    for (int ct = 0; ct < 3; ++ct) {
        const float bj = b2[wc * 48 + ct * 16 + l15];
        acc2[ct] = (f32x4){bj, bj, bj, bj};
    }
    #pragma unroll
    for (int kc = 0; kc < DR; kc += 32) {
        const bf16x8 af = *(const bf16x8*)&hidb[wm * 16 + l15][kc + 8 * lq];
        #pragma unroll
        for (int ct = 0; ct < 3; ++ct) {
            const bf16x8 bf = *(const bf16x8*)(W2T + (size_t)(wc * 48 + ct * 16 + l15) * DR + kc + 8 * lq);
            acc2[ct] = __builtin_amdgcn_mfma_f32_16x16x32_bf16(af, bf, acc2[ct], 0, 0, 0);
        }
    }
    __syncthreads();   // all hidb reads done; reuse as logits buffer

    #pragma unroll
    for (int ct = 0; ct < 3; ++ct)
        #pragma unroll
        for (int r = 0; r < 4; ++r)
            hidb[wm * 16 + lq * 4 + r][wc * 48 + ct * 16 + l15] = f2bf(acc2[ct][r]);
    __syncthreads();

    // ---- softmax over k (logit col = k*6+h) -> msc[n][h*16+k] bf16 ----
    if (t < 192) {
        const int r = t / 6, h = t - r * 6;
        float lg[KK];
        float mx = -1e30f;
        #pragma unroll
        for (int k = 0; k < KK; ++k) {
            lg[k] = __uint_as_float((unsigned)hidb[r][6 * k + h] << 16);
            mx = fmaxf(mx, lg[k]);
        }
        float s = 0.f;
        #pragma unroll
        for (int k = 0; k < KK; ++k) { lg[k] = __expf(lg[k] - mx); s += lg[k]; }
        const float inv = 1.0f / s;
        unsigned o[8];
        #pragma unroll
        for (int jj = 0; jj < 8; ++jj)
            o[jj] = pk2bf(lg[2 * jj] * inv, lg[2 * jj + 1] * inv);
        unsigned* op = (unsigned*)&msc[r][16 * h];
        *(uint4*)op       = make_uint4(o[0], o[1], o[2], o[3]);
        *(uint4*)(op + 4) = make_uint4(o[4], o[5], o[6], o[7]);
    }
    __syncthreads();   // hidb is DEAD from here -> reused as abuf

    // ---- Phase 2: LDS-pipelined A-form producer, coalesced write-out ----
    const bf16x8 z8 = {0, 0, 0, 0, 0, 0, 0, 0};
    const f32x4  cz = {0.f, 0.f, 0.f, 0.f};
    const size_t bc6 = ((size_t)b * NCHUNK + nc) * HH;
    const int  rw  = w >> 1;              // n-row within pair (0/1)
    const int  mh  = w & 1;               // m-half: 0 -> tiles 0..6, 1 -> 7..12
    const bool hv  = (l15 < HH);          // valid h column
    const bool kv  = (lq < 2);            // lanes holding k<16 (others annihilated)

    // abuf[nl2][h][m] bf16 = 4992 B, overlaid on dead hidb (6656 B)
    unsigned short (*abuf)[HH][MP] = (unsigned short (*)[HH][MP])&hidb[0][0];

    for (int r = 0; r < 16; ++r) {
        if (r) __syncthreads();           // round r-1 MFMA->abuf done; wbuf reads done

        // ---- write staged regs -> wbuf[r&1] (linear copy) ----
        {
            uint4* dp = (uint4*)&wbuf[r & 1][0][0][0];
            dp[t]       = av0;
            dp[t + 256] = av1;
            dp[t + 512] = av2;
            if (t < 64) dp[t + 768] = av3;
        }
        // ---- issue next round's global loads BEFORE compute ----
        if (r + 1 < 16) {
            const uint4* sp = (const uint4*)slab + (size_t)(r + 1) * 832;
            av0 = sp[t];
            av1 = sp[t + 256];
            av2 = sp[t + 512];
            if (t < 64) av3 = sp[t + 768];
        }
        // ---- coalesced copy-out of round r-1's A values (12 x 416B runs) ----
        if (r) {
            const int nlb = 2 * (r - 1);
            for (int i = t; i < 312; i += 256) {
                const int run = i / 26, off = i - run * 26;   // 26 uint4 per run
                const int nl2 = run & 1, hl = run >> 1;
                *(uint4*)(A + (bc6 + hl) * PLANE + (size_t)(nlb + nl2) * MP + off * 8)
                    = *(const uint4*)&abuf[nl2][hl][off * 8];
            }
        }
        __syncthreads();                  // wbuf ready; abuf drained

        // ---- compute: n-row nl = 2r + rw; results -> abuf (LDS) ----
        const int nl = 2 * r + rw;
        const bf16x8 bmix = (hv && kv)
            ? *(const bf16x8*)&msc[nl][l15 * 16 + 8 * lq] : z8;
        const unsigned short* wrow = &wbuf[r & 1][rw][0][0];   // 208 x 16
        if (mh == 0) {
            #pragma unroll
            for (int mt = 0; mt < 7; ++mt) {
                const bf16x8 afr = *(const bf16x8*)(wrow + (mt * 16 + l15) * 16 + 8 * lq);
                const f32x4 c = __builtin_amdgcn_mfma_f32_16x16x32_bf16(afr, bmix, cz, 0, 0, 0);
                if (hv)
                    *(uint2*)&abuf[rw][l15][mt * 16 + lq * 4] =
                        make_uint2(pk2bf(c[0], c[1]), pk2bf(c[2], c[3]));
            }
        } else {
            #pragma unroll
            for (int mt = 7; mt < 13; ++mt) {
                const bf16x8 afr = *(const bf16x8*)(wrow + (mt * 16 + l15) * 16 + 8 * lq);
                const f32x4 c = __builtin_amdgcn_mfma_f32_16x16x32_bf16(afr, bmix, cz, 0, 0, 0);
                if (hv)
                    *(uint2*)&abuf[rw][l15][mt * 16 + lq * 4] =
                        make_uint2(pk2bf(c[0], c[1]), pk2bf(c[2], c[3]));
            }
        }
    }
    __syncthreads();
    {   // ---- epilogue: copy round 15 ----
        for (int i = t; i < 312; i += 256) {
            const int run = i / 26, off = i - run * 26;
            const int nl2 = run & 1, hl = run >> 1;
            *(uint4*)(A + (bc6 + hl) * PLANE + (size_t)(30 + nl2) * MP + off * 8)
                = *(const uint4*)&abuf[nl2][hl][off * 8];
        }
    }
}

// ---------------------------------------------------------------------------
// Consumer GEMM — round-2 form (measured 46.6-47.8 us, 2.08 TB/s).
// ---------------------------------------------------------------------------
__global__ __launch_bounds__(192, 3) void mix_gemm_kernel(
    const float* __restrict__ x, const unsigned short* __restrict__ Ab,
    float* __restrict__ out)
{
    __shared__ unsigned short xT[192][40];   // [c_local][n] bf16, 15360 B
    __shared__ unsigned short As[3][32][68]; // [h_local][n][m_local] bf16, 13056 B

    const int t    = threadIdx.x;
    const int bid  = blockIdx.x;
    const int b    = bid & 127;       // bid%8 == b%8 -> same-b blocks share an XCD
    const int sub  = bid >> 7;        // 0..7
    const int q    = sub >> 1;        // m-quarter
    const int hp   = sub & 1;         // head triple
    const int m0   = q * 52;
    const int qvalid = (q == 3) ? 40 : 52;
    const int lw   = t >> 6;          // local head 0..2
    const int hbase = hp * 3;
    const int lane = t & 63;
    const int l15  = lane & 15;
    const int lq   = lane >> 4;
    const int c0   = hp * 192;        // channel slice of this head triple

    const f32x4 cz = {0.f, 0.f, 0.f, 0.f};
    f32x4 acc[4][4];
    #pragma unroll
    for (int mt = 0; mt < 4; ++mt)
        #pragma unroll
        for (int ct = 0; ct < 4; ++ct) acc[mt][ct] = cz;

    for (int nc = 0; nc < NCHUNK; ++nc) {
        const int n0 = nc * 32;
        __syncthreads();   // previous chunk's MFMA reads done

        // ---- A-slab loads: 96 rows (3h x 32n) x 128B, coalesced u64 ----
        unsigned long long av[8];
        const size_t bc6 = ((size_t)b * NCHUNK + nc) * HH + hbase;
        #pragma unroll
        for (int i = 0; i < 8; ++i) {
            const int P = t + 192 * i;        // 0..1535
            const int row = P >> 4, p = P & 15;
            const int hl = row >> 5, n = row & 31;
            av[i] = *(const unsigned long long*)(
                Ab + (bc6 + hl) * PLANE + (size_t)n * MP + m0 + 4 * p);
        }

        // ---- stage x -> xT bf16 transposed (this triple's 192 channels) ----
        #pragma unroll
        for (int it = 0; it < 4; ++it) {
            const int task = t + 192 * it;      // 0..767
            const int p  = task & 15;           // n-pair 0..15
            const int cq = task >> 4;           // c-quad 0..47
            const int n  = n0 + 2 * p;
            float4 va = make_float4(0.f, 0.f, 0.f, 0.f);
            float4 vb = make_float4(0.f, 0.f, 0.f, 0.f);
            if (n < NN)     va = *(const float4*)(x + ((size_t)b * NN + n) * CDIM + c0 + 4 * cq);
            if (n + 1 < NN) vb = *(const float4*)(x + ((size_t)b * NN + n + 1) * CDIM + c0 + 4 * cq);
            *(unsigned*)&xT[4 * cq + 0][2 * p] = pk2bf(va.x, vb.x);
            *(unsigned*)&xT[4 * cq + 1][2 * p] = pk2bf(va.y, vb.y);
            *(unsigned*)&xT[4 * cq + 2][2 * p] = pk2bf(va.z, vb.z);
            *(unsigned*)&xT[4 * cq + 3][2 * p] = pk2bf(va.w, vb.w);
        }

        // ---- write A-slab to LDS (8B stores, conflict-free) ----
        #pragma unroll
        for (int i = 0; i < 8; ++i) {
            const int P = t + 192 * i;
            const int row = P >> 4, p = P & 15;
            *(unsigned long long*)&As[row >> 5][row & 31][4 * p] = av[i];
        }
        __syncthreads();

        // ---- A-frags via u16 gathers (transpose-on-read), then 16 MFMA ----
        bf16x8 afr[4], bfr[4];
        #pragma unroll
        for (int mt = 0; mt < 4; ++mt) {
            union { unsigned short s[8]; bf16x8 v; } u;
            #pragma unroll
            for (int j = 0; j < 8; ++j)
                u.s[j] = As[lw][8 * lq + j][mt * 16 + l15];
            afr[mt] = u.v;
        }
        #pragma unroll
        for (int ct = 0; ct < 4; ++ct)
            bfr[ct] = *(const bf16x8*)&xT[lw * 64 + ct * 16 + l15][8 * lq];
        #pragma unroll
        for (int mt = 0; mt < 4; ++mt)
            #pragma unroll
            for (int ct = 0; ct < 4; ++ct)
                acc[mt][ct] = __builtin_amdgcn_mfma_f32_16x16x32_bf16(
                    afr[mt], bfr[ct], acc[mt][ct], 0, 0, 0);
    }

    // ---- epilogue: C/D layout col=l15 (c), row=lq*4+r (m) ----
    const int h = hbase + lw;
    #pragma unroll
    for (int mt = 0; mt < 4; ++mt) {
        #pragma unroll
        for (int r = 0; r < 4; ++r) {
            const int ms = mt * 16 + lq * 4 + r;
            if (ms < qvalid) {
                float* op = out + ((size_t)b * NN + m0 + ms) * CDIM + h * HD + l15;
                #pragma unroll
                for (int ct = 0; ct < 4; ++ct)
                    op[ct * 16] = acc[mt][ct][r];
            }
        }
    }
}

// ---------------------------------------------------------------------------
// Fallback path (small workspace): standalone adapter + fused mix kernel.
// ---------------------------------------------------------------------------
__global__ __launch_bounds__(128, 3) void adapter_kernel(
    const float* __restrict__ x,   const unsigned short* __restrict__ W1T,
    const float* __restrict__ b1,  const unsigned short* __restrict__ W2T,
    const float* __restrict__ b2,  unsigned short* __restrict__ mix_out)
{
    __shared__ unsigned short hidb[16][104];

    const int t    = threadIdx.x;
    const int wc   = t >> 6;
    const int lane = t & 63;
    const int l15  = lane & 15;
    const int lq   = lane >> 4;
    const int row0 = blockIdx.x * 16;

    f32x4 acc[3];
    #pragma unroll
    for (int ct = 0; ct < 3; ++ct) {
        const float bj = b1[wc * 48 + ct * 16 + l15];
        acc[ct] = (f32x4){bj, bj, bj, bj};
    }
    const float* xrow = x + (size_t)(row0 + l15) * CDIM;
    for (int kc = 0; kc < CDIM; kc += 32) {
        const float4 u = *(const float4*)(xrow + kc + 8 * lq);
        const float4 v = *(const float4*)(xrow + kc + 8 * lq + 4);
        AFrag af;
        af.u[0] = pk2bf(u.x, u.y); af.u[1] = pk2bf(u.z, u.w);
        af.u[2] = pk2bf(v.x, v.y); af.u[3] = pk2bf(v.z, v.w);
        #pragma unroll
        for (int ct = 0; ct < 3; ++ct) {
            const bf16x8 bf = *(const bf16x8*)(W1T + (size_t)(wc * 48 + ct * 16 + l15) * CDIM + kc + 8 * lq);
            acc[ct] = __builtin_amdgcn_mfma_f32_16x16x32_bf16(af.f, bf, acc[ct], 0, 0, 0);
        }
    }
    #pragma unroll
    for (int ct = 0; ct < 3; ++ct)
        #pragma unroll
        for (int r = 0; r < 4; ++r) {
            const float vv = acc[ct][r];
            hidb[lq * 4 + r][wc * 48 + ct * 16 + l15] =
                f2bf(0.5f * vv * (1.0f + erff(vv * 0.70710678118654752f)));
        }
    __syncthreads();

    f32x4 acc2[3];
    #pragma unroll
    for (int ct = 0; ct < 3; ++ct) {
        const float bj = b2[wc * 48 + ct * 16 + l15];
        acc2[ct] = (f32x4){bj, bj, bj, bj};
    }
    #pragma unroll
    for (int kc = 0; kc < DR; kc += 32) {
        const bf16x8 af = *(const bf16x8*)&hidb[l15][kc + 8 * lq];
        #pragma unroll
        for (int ct = 0; ct < 3; ++ct) {
            const bf16x8 bf = *(const bf16x8*)(W2T + (size_t)(wc * 48 + ct * 16 + l15) * DR + kc + 8 * lq);
            acc2[ct] = __builtin_amdgcn_mfma_f32_16x16x32_bf16(af, bf, acc2[ct], 0, 0, 0);
        }
    }
    __syncthreads();

    #pragma unroll
    for (int ct = 0; ct < 3; ++ct)
        #pragma unroll
        for (int r = 0; r < 4; ++r)
            hidb[lq * 4 + r][wc * 48 + ct * 16 + l15] = f2bf(acc2[ct][r]);
    __syncthreads();

    if (t < 96) {
        const int r = t / 6, h = t % 6;
        float lg[KK];
        float mx = -1e30f;
        #pragma unroll
        for (int k = 0; k < KK; ++k) {
            lg[k] = __uint_as_float((unsigned)hidb[r][6 * k + h] << 16);
            mx = fmaxf(mx, lg[k]);
        }
        float s = 0.f;
        #pragma unroll
        for (int k = 0; k < KK; ++k) { lg[k] = __expf(lg[k] - mx); s += lg[k]; }
        const float inv = 1.0f / s;
        unsigned o[8];
        #pragma unroll
        for (int jj = 0; jj < 8; ++jj)
            o[jj] = pk2bf(lg[2 * jj] * inv, lg[2 * jj + 1] * inv);
        unsigned* op = (unsigned*)(mix_out + ((size_t)(row0 + r) * HH + h) * KK);
        *(uint4*)op       = make_uint4(o[0], o[1], o[2], o[3]);
        *(uint4*)(op + 4) = make_uint4(o[4], o[5], o[6], o[7]);
    }
}

__global__ __launch_bounds__(192, 3) void mix_mfma_fb_kernel(
    const float* __restrict__ x,  const unsigned short* __restrict__ mixb,
    const unsigned short* __restrict__ wbT, float* __restrict__ out)
{
    __shared__ unsigned short xT[192][40];
    __shared__ unsigned short Asb[3][64][40];

    const int t    = threadIdx.x;
    const int bid  = blockIdx.x;
    const int b    = bid & 127;
    const int sub  = bid >> 7;
    const int q    = sub >> 1;
    const int hp   = sub & 1;
    const int m0   = q * 52;
    const int qvalid = (q == 3) ? 40 : 52;
    const int lw   = t >> 6;
    const int hbase = hp * 3;
    const int lane = t & 63;
    const int l15  = lane & 15;
    const int lq   = lane >> 4;
    const int c0   = hp * 192;

    const bf16x8 z8 = {0, 0, 0, 0, 0, 0, 0, 0};
    const f32x4  cz = {0.f, 0.f, 0.f, 0.f};

    f32x4 acc[4][4];
    #pragma unroll
    for (int mt = 0; mt < 4; ++mt)
        #pragma unroll
        for (int ct = 0; ct < 4; ++ct) acc[mt][ct] = cz;

    for (int nc = 0; nc < 7; ++nc) {
        const int n0 = nc * 32;
        __syncthreads();

        #pragma unroll
        for (int it = 0; it < 4; ++it) {
            const int task = t + 192 * it;
            const int p  = task & 15;
            const int cq = task >> 4;
            const int n  = n0 + 2 * p;
            float4 va = make_float4(0.f, 0.f, 0.f, 0.f);
            float4 vb = make_float4(0.f, 0.f, 0.f, 0.f);
            if (n < NN)     va = *(const float4*)(x + ((size_t)b * NN + n) * CDIM + c0 + 4 * cq);
            if (n + 1 < NN) vb = *(const float4*)(x + ((size_t)b * NN + n + 1) * CDIM + c0 + 4 * cq);
            *(unsigned*)&xT[4 * cq + 0][2 * p] = pk2bf(va.x, vb.x);
            *(unsigned*)&xT[4 * cq + 1][2 * p] = pk2bf(va.y, vb.y);
            *(unsigned*)&xT[4 * cq + 2][2 * p] = pk2bf(va.z, vb.z);
            *(unsigned*)&xT[4 * cq + 3][2 * p] = pk2bf(va.w, vb.w);
        }

        for (int nl = lw; nl < 32; nl += 3) {
            const int n = n0 + nl;
            if (n < NN) {
                bf16x8 af = z8;
                if (l15 < HH && lq < 2)
                    af = *(const bf16x8*)(mixb + (((size_t)b * NN + n) * HH + l15) * KK + 8 * lq);
                #pragma unroll
                for (int mt = 0; mt < 4; ++mt) {
                    const int m = m0 + mt * 16 + l15;
                    bf16x8 bf = z8;
                    if (lq < 2 && m < NN)
                        bf = *(const bf16x8*)(wbT + ((size_t)n * MP + m) * KK + 8 * lq);
                    const f32x4 c = __builtin_amdgcn_mfma_f32_16x16x32_bf16(af, bf, cz, 0, 0, 0);
                    #pragma unroll
                    for (int r = 0; r < 4; ++r) {
                        const int hh = lq * 4 + r;
                        if (hh >= hbase && hh < hbase + 3)
                            Asb[hh - hbase][mt * 16 + l15][nl] = f2bf(c[r]);
                    }
                }
            } else {
                #pragma unroll
                for (int mt = 0; mt < 4; ++mt)
                    #pragma unroll
                    for (int r = 0; r < 4; ++r) {
                        const int hh = lq * 4 + r;
                        if (hh >= hbase && hh < hbase + 3)
                            Asb[hh - hbase][mt * 16 + l15][nl] = 0;
                    }
            }
        }
        __syncthreads();

        bf16x8 afr[4], bfr[4];
        #pragma unroll
        for (int mt = 0; mt < 4; ++mt)
            afr[mt] = *(const bf16x8*)&Asb[lw][mt * 16 + l15][8 * lq];
        #pragma unroll
        for (int ct = 0; ct < 4; ++ct)
            bfr[ct] = *(const bf16x8*)&xT[lw * 64 + ct * 16 + l15][8 * lq];
        #pragma unroll
        for (int mt = 0; mt < 4; ++mt)
            #pragma unroll
            for (int ct = 0; ct < 4; ++ct)
                acc[mt][ct] = __builtin_amdgcn_mfma_f32_16x16x32_bf16(
                    afr[mt], bfr[ct], acc[mt][ct], 0, 0, 0);
    }

    const int h = hbase + lw;
    #pragma unroll
    for (int mt = 0; mt < 4; ++mt) {
        #pragma unroll
        for (int r = 0; r < 4; ++r) {
            const int ms = mt * 16 + lq * 4 + r;
            if (ms < qvalid) {
                float* op = out + ((size_t)b * NN + m0 + ms) * CDIM + h * HD + l15;
                #pragma unroll
                for (int ct = 0; ct < 4; ++ct)
                    op[ct * 16] = acc[mt][ct][r];
            }
        }
    }
}

extern "C" void kernel_launch(void* const* d_in, const int* in_sizes, int n_in,
                              void* d_out, int out_size, void* d_ws, size_t ws_size,
                              hipStream_t stream) {
    (void)in_sizes; (void)n_in; (void)out_size;
    const float* x  = (const float*)d_in[0];
    const float* W1 = (const float*)d_in[1];
    const float* b1 = (const float*)d_in[2];
    const float* W2 = (const float*)d_in[3];
    const float* b2 = (const float*)d_in[4];
    const float* wb = (const float*)d_in[5];
    float* out = (float*)d_out;

    // workspace layout (1KB slack after wbT for unconditional tail overread)
    const size_t W1T_OFF  = 0;                 //    73,728 B
    const size_t W2T_OFF  = 73728;             //    18,432 B
    const size_t WBT_OFF  = 92160;             // 1,490,944 B (224*208*16*2)
    const size_t A_OFF    = 1584128;           // 71,565,312 B
    const size_t NEED     = A_OFF + 71565312ull + 1024ull;

    unsigned short* w1t = (unsigned short*)((char*)d_ws + W1T_OFF);
    unsigned short* w2t = (unsigned short*)((char*)d_ws + W2T_OFF);
    unsigned short* wbt = (unsigned short*)((char*)d_ws + WBT_OFF);

    prep_kernel<<<DR + 224, 256, 0, stream>>>(W1, W2, wb, w1t, w2t, wbt);

    if (ws_size >= NEED) {
        unsigned short* Ab = (unsigned short*)((char*)d_ws + A_OFF);
        mixa_kernel<<<BB * NCHUNK, 256, 0, stream>>>(x, w1t, b1, w2t, b2, wbt, Ab);
        mix_gemm_kernel<<<8 * BB, 192, 0, stream>>>(x, Ab, out);
    } else {
        unsigned short* mixbuf = (unsigned short*)((char*)d_ws + A_OFF);  // reuse
        adapter_kernel<<<(BB * NN) / 16, 128, 0, stream>>>(x, w1t, b1, w2t, b2, mixbuf);
        mix_mfma_fb_kernel<<<8 * BB, 192, 0, stream>>>(x, mixbuf, wbt, out);
    }
}